// Round 6
// baseline (43.681 us; speedup 1.0000x reference)
//
#include <hip/hip_runtime.h>
#include <math.h>

// TransE: out[b,e] = sigmoid(12 - sum_d |(ent_w[sub[b]]+rel_w[rel[b]])[d] - ent_w[e][d]|)
// b in [0,64), e in [0,100000), d in [0,128). f32 in/out.
//
// Round-6: u16 fixed-point + v_sad_u16 (1 instr per 2 dims; was 3 per 2).
//  - Quantize at stage time: u = trunc(x*2^18 + 32768.5). |q|<=0.106 -> u in
//    [~5k,60k], never clamps. |qi-ei| exact linear (offsets cancel); dist err
//    <= 128*2^-18 ~ 5e-4 -> output err ~1e-4 (BETTER than the f16 path's 0.0117).
//  - Now LDS-instr-bound, so economize ds_reads: 128-thr blocks, 8b x 8e
//    per-thread tile -> 16 ds_read_b128 per 256 SADs (1:16), register
//    double-buffer of chunks (~210 VGPR, fits 2 waves/SIMD).
//  - Batch rows b = tb + 8*i: qf[i]'s 4 wave-addresses land on distinct banks
//    (old tb*4+i stride 544B = same-bank 4-way).
//  - Budget: LDS ~9us, HBM ~8us, VALU ~4.6us -> target 13-18us.
//  - Hedge: if __builtin_amdgcn_sad_u16 is unavailable, fall back to the
//    round-5 f16/fdot2 kernel (passed at 38us).

#define NUM_ENT 100000
#define EMB_DIM 128
#define GAMMA_F 12.0f
#define BATCH 64
#define E_TILE 128
#define ROW_U32 68   // 64 u32 (128 u16/f16) + 4 pad -> 272B row stride, 16B aligned

typedef float f32x4 __attribute__((ext_vector_type(4)));
typedef unsigned int u32;
typedef u32 u32x4 __attribute__((ext_vector_type(4)));

#if __has_builtin(__builtin_amdgcn_sad_u16)
// ============================ SAD u16 path ============================

#define THREADS 128
#define QSCALE 262144.0f      // 2^18
#define QBIAS 32768.5f        // +0.125*2^18 offset, +0.5 for round-nearest via trunc
#define INV_QSCALE 3.814697265625e-06f  // 2^-18

__device__ __forceinline__ u32 quant2(float x0, float x1) {
    u32 a = (u32)fmaf(x0, QSCALE, QBIAS);   // v_fma_f32 + v_cvt_u32_f32
    u32 b = (u32)fmaf(x1, QSCALE, QBIAS);
    return a | (b << 16);
}

__global__ __launch_bounds__(THREADS, 2) void transe_sad_kernel(
    const int* __restrict__ sub, const int* __restrict__ rel,
    const float* __restrict__ ent_w, const float* __restrict__ rel_w,
    float* __restrict__ out)
{
    __shared__ u32 qlds[BATCH * ROW_U32];    // 17408 B
    __shared__ u32 elds[E_TILE * ROW_U32];   // 34816 B  (total 52224 -> 3 blocks/CU)

    const int tid = threadIdx.x;
    const int e0 = blockIdx.x * E_TILE;

    // ---- stage q = ent_w[sub]+rel_w[rel], f32 -> u16 fixed point ----
#pragma unroll
    for (int it = 0; it < 8; ++it) {
        int idx = (it * THREADS + tid) * 8;
        int b = idx >> 7, d = idx & 127;
        const float* sp = ent_w + (size_t)sub[b] * EMB_DIM + d;
        const float* rp = rel_w + (size_t)rel[b] * EMB_DIM + d;
        f32x4 a0 = *(const f32x4*)sp + *(const f32x4*)rp;
        f32x4 a1 = *(const f32x4*)(sp + 4) + *(const f32x4*)(rp + 4);
        u32x4 w;
        w.x = quant2(a0.x, a0.y); w.y = quant2(a0.z, a0.w);
        w.z = quant2(a1.x, a1.y); w.w = quant2(a1.z, a1.w);
        *(u32x4*)&qlds[b * ROW_U32 + (d >> 1)] = w;
    }

    // ---- stage e-tile rows, f32 -> u16 fixed point ----
#pragma unroll
    for (int it = 0; it < 8; ++it) {
        int idx = (it * THREADS + tid) * 16;
        int row = idx >> 7, d = idx & 127;
        int ge = e0 + row; if (ge > NUM_ENT - 1) ge = NUM_ENT - 1;  // clamp tail
        const float* ep = ent_w + (size_t)ge * EMB_DIM + d;
        f32x4 a0 = *(const f32x4*)ep;
        f32x4 a1 = *(const f32x4*)(ep + 4);
        f32x4 a2 = *(const f32x4*)(ep + 8);
        f32x4 a3 = *(const f32x4*)(ep + 12);
        u32x4 w0, w1;
        w0.x = quant2(a0.x, a0.y); w0.y = quant2(a0.z, a0.w);
        w0.z = quant2(a1.x, a1.y); w0.w = quant2(a1.z, a1.w);
        w1.x = quant2(a2.x, a2.y); w1.y = quant2(a2.z, a2.w);
        w1.z = quant2(a3.x, a3.y); w1.w = quant2(a3.z, a3.w);
        *(u32x4*)&elds[row * ROW_U32 + (d >> 1)] = w0;
        *(u32x4*)&elds[row * ROW_U32 + (d >> 1) + 4] = w1;
    }

    __syncthreads();  // the only barrier

    // ---- compute: thread = 8 batches (tb+8i) x 8 entities (te+16j) ----
    const int te = tid & 15;
    const int tb = tid >> 4;  // 0..7

    u32 acc[8][8] = {};

    const u32* __restrict__ qbase = &qlds[tb * ROW_U32];
    const u32* __restrict__ ebase = &elds[te * ROW_U32];

    u32x4 qA[8], eA[8], qB[8], eB[8];

#define LOADQ(dst, c) do { _Pragma("unroll") \
    for (int i = 0; i < 8; ++i) dst[i] = *(const u32x4*)&qbase[i * 8 * ROW_U32 + (c) * 4]; } while (0)
#define LOADE(dst, c) do { _Pragma("unroll") \
    for (int j = 0; j < 8; ++j) dst[j] = *(const u32x4*)&ebase[j * 16 * ROW_U32 + (c) * 4]; } while (0)
#define SADALL(qv, ev) do { _Pragma("unroll") \
    for (int i = 0; i < 8; ++i) { _Pragma("unroll") \
        for (int j = 0; j < 8; ++j) { _Pragma("unroll") \
            for (int k = 0; k < 4; ++k) \
                acc[i][j] = __builtin_amdgcn_sad_u16(qv[i][k], ev[j][k], acc[i][j]); } } } while (0)

    LOADQ(qA, 0); LOADE(eA, 0);
#pragma unroll 2
    for (int c = 0; c < 16; c += 2) {
        LOADQ(qB, c + 1); LOADE(eB, c + 1);
        SADALL(qA, eA);
        // c=14 prefetches "chunk 16" = the row pad region: in-bounds, never consumed.
        LOADQ(qA, c + 2); LOADE(eA, c + 2);
        SADALL(qB, eB);
    }

    // ---- epilogue: dist = acc * 2^-18 (offsets cancel), sigmoid, store ----
#pragma unroll
    for (int i = 0; i < 8; ++i) {
        int b = tb + 8 * i;
        float* __restrict__ orow = out + (size_t)b * NUM_ENT + e0 + te;
#pragma unroll
        for (int j = 0; j < 8; ++j) {
            int e = e0 + te + 16 * j;
            if (e < NUM_ENT) {
                float dist = (float)acc[i][j] * INV_QSCALE;
                orow[16 * j] = __builtin_amdgcn_rcpf(1.0f + __expf(dist - GAMMA_F));
            }
        }
    }
}

extern "C" void kernel_launch(void* const* d_in, const int* in_sizes, int n_in,
                              void* d_out, int out_size, void* d_ws, size_t ws_size,
                              hipStream_t stream) {
    const int* sub = (const int*)d_in[0];
    const int* rel = (const int*)d_in[1];
    const float* ent_w = (const float*)d_in[2];
    const float* rel_w = (const float*)d_in[3];
    float* out = (float*)d_out;
    dim3 grid((NUM_ENT + E_TILE - 1) / E_TILE);  // 782
    transe_sad_kernel<<<grid, dim3(THREADS), 0, stream>>>(sub, rel, ent_w, rel_w, out);
}

#else
// ======================= fallback: round-5 f16 path =======================

#define THREADS 256
#define CHUNKS 16
typedef _Float16 h2 __attribute__((ext_vector_type(2)));
typedef __fp16 h2b __attribute__((ext_vector_type(2)));

__device__ __forceinline__ u32 pkrtz(float a, float b) {
    auto p = __builtin_amdgcn_cvt_pkrtz(a, b);
    return __builtin_bit_cast(u32, p);
}
__device__ __forceinline__ float fdot2_acc(u32 ab, u32 ones, float acc) {
    return __builtin_amdgcn_fdot2(__builtin_bit_cast(h2b, ab),
                                  __builtin_bit_cast(h2b, ones), acc, false);
}

__global__ __launch_bounds__(THREADS, 3) void transe_score_kernel(
    const int* __restrict__ sub, const int* __restrict__ rel,
    const float* __restrict__ ent_w, const float* __restrict__ rel_w,
    float* __restrict__ out)
{
    __shared__ u32 qlds[BATCH * ROW_U32];
    __shared__ u32 elds[E_TILE * ROW_U32];
    const int tid = threadIdx.x;
    const int e0 = blockIdx.x * E_TILE;

#pragma unroll
    for (int it = 0; it < (BATCH * EMB_DIM) / (THREADS * 16); ++it) {
        int idx = (it * THREADS + tid) * 16;
        int b = idx >> 7, d = idx & 127;
        const float* sp = ent_w + (size_t)sub[b] * EMB_DIM + d;
        const float* rp = rel_w + (size_t)rel[b] * EMB_DIM + d;
        u32x4 w0, w1;
        { f32x4 a0 = *(const f32x4*)sp + *(const f32x4*)rp;
          f32x4 a1 = *(const f32x4*)(sp + 4) + *(const f32x4*)(rp + 4);
          w0.x = pkrtz(a0.x, a0.y); w0.y = pkrtz(a0.z, a0.w);
          w0.z = pkrtz(a1.x, a1.y); w0.w = pkrtz(a1.z, a1.w); }
        { f32x4 a0 = *(const f32x4*)(sp + 8) + *(const f32x4*)(rp + 8);
          f32x4 a1 = *(const f32x4*)(sp + 12) + *(const f32x4*)(rp + 12);
          w1.x = pkrtz(a0.x, a0.y); w1.y = pkrtz(a0.z, a0.w);
          w1.z = pkrtz(a1.x, a1.y); w1.w = pkrtz(a1.z, a1.w); }
        *(u32x4*)&qlds[b * ROW_U32 + (d >> 1)] = w0;
        *(u32x4*)&qlds[b * ROW_U32 + (d >> 1) + 4] = w1;
    }
#pragma unroll
    for (int it = 0; it < (E_TILE * EMB_DIM) / (THREADS * 16); ++it) {
        int idx = (it * THREADS + tid) * 16;
        int row = idx >> 7, d = idx & 127;
        int ge = e0 + row; if (ge > NUM_ENT - 1) ge = NUM_ENT - 1;
        const float* ep = ent_w + (size_t)ge * EMB_DIM + d;
        u32x4 w0, w1;
        { f32x4 a0 = *(const f32x4*)ep; f32x4 a1 = *(const f32x4*)(ep + 4);
          w0.x = pkrtz(a0.x, a0.y); w0.y = pkrtz(a0.z, a0.w);
          w0.z = pkrtz(a1.x, a1.y); w0.w = pkrtz(a1.z, a1.w); }
        { f32x4 a0 = *(const f32x4*)(ep + 8); f32x4 a1 = *(const f32x4*)(ep + 12);
          w1.x = pkrtz(a0.x, a0.y); w1.y = pkrtz(a0.z, a0.w);
          w1.z = pkrtz(a1.x, a1.y); w1.w = pkrtz(a1.z, a1.w); }
        *(u32x4*)&elds[row * ROW_U32 + (d >> 1)] = w0;
        *(u32x4*)&elds[row * ROW_U32 + (d >> 1) + 4] = w1;
    }
    __syncthreads();

    const int te = tid & 15;
    const int tb = tid >> 4;
    float acc[4][8];
#pragma unroll
    for (int i = 0; i < 4; ++i)
#pragma unroll
        for (int j = 0; j < 8; ++j) acc[i][j] = 0.0f;
    const u32* __restrict__ qbase = &qlds[(tb * 4) * ROW_U32];
    const u32* __restrict__ ebase = &elds[te * ROW_U32];
    const u32 ones = 0x3C003C00u;
#pragma unroll 1
    for (int c = 0; c < CHUNKS; ++c) {
        u32x4 qf[4];
#pragma unroll
        for (int i = 0; i < 4; ++i) qf[i] = *(const u32x4*)&qbase[i * ROW_U32 + c * 4];
#pragma unroll
        for (int j = 0; j < 8; ++j) {
            u32x4 ef = *(const u32x4*)&ebase[(16 * j) * ROW_U32 + c * 4];
#pragma unroll
            for (int i = 0; i < 4; ++i) {
#pragma unroll
                for (int k = 0; k < 4; ++k) {
                    h2 qv = __builtin_bit_cast(h2, qf[i][k]);
                    h2 ev = __builtin_bit_cast(h2, ef[k]);
                    h2 dd = qv - ev;
                    u32 ab = __builtin_bit_cast(u32, dd) & 0x7FFF7FFFu;
                    acc[i][j] = fdot2_acc(ab, ones, acc[i][j]);
                }
            }
        }
    }
#pragma unroll
    for (int i = 0; i < 4; ++i) {
        int b = tb * 4 + i;
        float* __restrict__ orow = out + (size_t)b * NUM_ENT + e0 + te;
#pragma unroll
        for (int j = 0; j < 8; ++j) {
            int e = e0 + te + 16 * j;
            if (e < NUM_ENT)
                orow[16 * j] = __builtin_amdgcn_rcpf(1.0f + __expf(acc[i][j] - GAMMA_F));
        }
    }
}

extern "C" void kernel_launch(void* const* d_in, const int* in_sizes, int n_in,
                              void* d_out, int out_size, void* d_ws, size_t ws_size,
                              hipStream_t stream) {
    const int* sub = (const int*)d_in[0];
    const int* rel = (const int*)d_in[1];
    const float* ent_w = (const float*)d_in[2];
    const float* rel_w = (const float*)d_in[3];
    float* out = (float*)d_out;
    dim3 grid((NUM_ENT + E_TILE - 1) / E_TILE);
    transe_score_kernel<<<grid, dim3(THREADS), 0, stream>>>(sub, rel, ent_w, rel_w, out);
}
#endif

// Round 7
// 37.808 us; speedup vs baseline: 1.1553x; 1.1553x over previous
//
#include <hip/hip_runtime.h>
#include <math.h>

// TransE: out[b,e] = sigmoid(12 - sum_d |(ent_w[sub[b]]+rel_w[rel[b]])[d] - ent_w[e][d]|)
// b in [0,64), e in [0,100000), d in [0,128). f32 in/out.
//
// Round-7: SAD u16 (R6 math) + concurrency/tail fixes.
//  - R6 failure mode: 128-thr blocks -> 6 waves/CU, occupancy 9.6%, latency-bound;
//    grid 782 on 768 slots -> second dispatch round at 5% util.
//  - Now: 256-thr blocks, split-K over dims (kd = tid>>7 owns 64 dims), per-thread
//    8b x 9e tile -> 12 waves/CU, LDS reads still 17 instr per 288 SADs.
//  - E_TILE=136, grid=736 <= 768: ONE dispatch round. LDS 54400 B = 3 blocks/CU.
//  - Partial-acc combine: kd=1 writes acc to reused elds (b32, lane-stride 4B,
//    conflict-free), kd=0 reads+adds+does epilogue. Once per block.
//  - Addressing: 1 base VGPR + immediate ds offsets (rows are compile-time
//    strides); keeps VGPR ~160 so __launch_bounds__(256,3) holds 3 waves/SIMD.
//  - Pipe budget/CU: VALU ~11.5us, LDS ~9us, HBM ~5-8us -> target 18-26us.

#define NUM_ENT 100000
#define EMB_DIM 128
#define GAMMA_F 12.0f
#define BATCH 64

#define THREADS 256
#define E_TILE 136
#define ROW_U32 68          // 64 data u32 (128 u16) + 4 pad -> 272B row stride
#define QLDS_U32 (BATCH * ROW_U32)    // 4352
#define ELDS_U32 (E_TILE * ROW_U32)   // 9248  (reduce scratch needs 9216 <= this)

#define QSCALE 262144.0f    // 2^18
#define QBIAS 32768.5f      // offset + 0.5 for round-nearest via trunc
#define INV_QSCALE 3.814697265625e-06f  // 2^-18

typedef float f32x4 __attribute__((ext_vector_type(4)));
typedef unsigned int u32;
typedef u32 u32x4 __attribute__((ext_vector_type(4)));

__device__ __forceinline__ u32 quant2(float x0, float x1) {
    u32 a = (u32)fmaf(x0, QSCALE, QBIAS);
    u32 b = (u32)fmaf(x1, QSCALE, QBIAS);
    return a | (b << 16);
}

__global__ __launch_bounds__(THREADS, 3) void transe_sad_kernel(
    const int* __restrict__ sub, const int* __restrict__ rel,
    const float* __restrict__ ent_w, const float* __restrict__ rel_w,
    float* __restrict__ out)
{
    __shared__ u32 qlds[QLDS_U32];   // 17408 B
    __shared__ u32 elds[ELDS_U32];   // 36992 B   (total 54400 -> 3 blocks/CU)

    const int tid = threadIdx.x;
    const int e0 = blockIdx.x * E_TILE;

    // ---- stage q = ent_w[sub]+rel_w[rel] -> u16 fixed point (4 iters) ----
#pragma unroll
    for (int it = 0; it < (BATCH * EMB_DIM) / (THREADS * 8); ++it) {
        int idx = (it * THREADS + tid) * 8;
        int b = idx >> 7, d = idx & 127;
        const float* sp = ent_w + (size_t)sub[b] * EMB_DIM + d;
        const float* rp = rel_w + (size_t)rel[b] * EMB_DIM + d;
        f32x4 a0 = *(const f32x4*)sp + *(const f32x4*)rp;
        f32x4 a1 = *(const f32x4*)(sp + 4) + *(const f32x4*)(rp + 4);
        u32x4 w;
        w.x = quant2(a0.x, a0.y); w.y = quant2(a0.z, a0.w);
        w.z = quant2(a1.x, a1.y); w.w = quant2(a1.z, a1.w);
        *(u32x4*)&qlds[b * ROW_U32 + (d >> 1)] = w;
    }

    // ---- stage e-tile rows (136 rows, clamped at dataset end) ----
#pragma unroll
    for (int it = 0; it < 9; ++it) {
        int idx = (it * THREADS + tid) * 8;
        if (idx < E_TILE * EMB_DIM) {
            int row = idx >> 7, d = idx & 127;
            int ge = e0 + row; if (ge > NUM_ENT - 1) ge = NUM_ENT - 1;
            const float* ep = ent_w + (size_t)ge * EMB_DIM + d;
            f32x4 a0 = *(const f32x4*)ep;
            f32x4 a1 = *(const f32x4*)(ep + 4);
            u32x4 w;
            w.x = quant2(a0.x, a0.y); w.y = quant2(a0.z, a0.w);
            w.z = quant2(a1.x, a1.y); w.w = quant2(a1.z, a1.w);
            *(u32x4*)&elds[row * ROW_U32 + (d >> 1)] = w;
        }
    }

    __syncthreads();

    // ---- compute: (kd, tb, te); thread = 8 batches x 9 entities x 64 dims ----
    const int te = tid & 15;          // e = te + 16j, j<9 (j=8 valid only te<8)
    const int tb = (tid >> 4) & 7;    // b = tb + 8i, i<8
    const int kd = tid >> 7;          // dim half [kd*64, kd*64+64)

    const u32* __restrict__ qaddr = &qlds[tb * ROW_U32 + kd * 32];
    const u32* __restrict__ eaddr = &elds[te * ROW_U32 + kd * 32];
    int er8 = te + 128; if (er8 > E_TILE - 1) er8 = E_TILE - 1;  // clamp 9th row addr
    const u32* __restrict__ eaddr8 = &elds[er8 * ROW_U32 + kd * 32];

    u32 acc[8][9] = {};

#pragma unroll 2
    for (int cc = 0; cc < 8; ++cc) {   // 8 chunks x 8 dims = 64 dims (this half)
        u32x4 qf[8];
        u32x4 ef[9];
#pragma unroll
        for (int i = 0; i < 8; ++i)
            qf[i] = *(const u32x4*)&qaddr[i * 8 * ROW_U32 + cc * 4];
#pragma unroll
        for (int j = 0; j < 8; ++j)
            ef[j] = *(const u32x4*)&eaddr[j * 16 * ROW_U32 + cc * 4];
        ef[8] = *(const u32x4*)&eaddr8[cc * 4];
#pragma unroll
        for (int i = 0; i < 8; ++i)
#pragma unroll
            for (int j = 0; j < 9; ++j)
#pragma unroll
                for (int k = 0; k < 4; ++k)
                    acc[i][j] = __builtin_amdgcn_sad_u16(qf[i][k], ef[j][k], acc[i][j]);
    }

    // ---- split-K combine: kd=1 -> LDS (reuse elds), kd=0 adds ----
    __syncthreads();  // all elds tile reads done
    const int half = tid & 127;
    u32* __restrict__ red = elds;     // 128 threads x 72 u32 = 9216 <= 9248
    if (kd == 1) {
#pragma unroll
        for (int i = 0; i < 8; ++i)
#pragma unroll
            for (int j = 0; j < 9; ++j)
                red[half + 128 * (i * 9 + j)] = acc[i][j];  // lane-stride 4B: conflict-free
    }
    __syncthreads();

    if (kd == 0) {
#pragma unroll
        for (int i = 0; i < 8; ++i) {
            int b = tb + 8 * i;
            float* __restrict__ orow = out + (size_t)b * NUM_ENT + e0 + te;
#pragma unroll
            for (int j = 0; j < 9; ++j) {
                u32 a = acc[i][j] + red[half + 128 * (i * 9 + j)];
                int le = te + 16 * j;
                if (le < E_TILE && e0 + le < NUM_ENT) {
                    float dist = (float)a * INV_QSCALE;
                    orow[16 * j] = __builtin_amdgcn_rcpf(1.0f + __expf(dist - GAMMA_F));
                }
            }
        }
    }
}

extern "C" void kernel_launch(void* const* d_in, const int* in_sizes, int n_in,
                              void* d_out, int out_size, void* d_ws, size_t ws_size,
                              hipStream_t stream) {
    const int* sub = (const int*)d_in[0];
    const int* rel = (const int*)d_in[1];
    const float* ent_w = (const float*)d_in[2];
    const float* rel_w = (const float*)d_in[3];
    float* out = (float*)d_out;

    dim3 grid((NUM_ENT + E_TILE - 1) / E_TILE);  // 736 <= 768 slots: one round
    transe_sad_kernel<<<grid, dim3(THREADS), 0, stream>>>(sub, rel, ent_w, rel_w, out);
}